// Round 13
// baseline (101.858 us; speedup 1.0000x reference)
//
#include <hip/hip_runtime.h>

#define STEPS 32768
#define DIO 63
#define HSZ 256
#define NL 6
#define BM 64
#define THREADS 1024

// Gate weights, A-role fragment order, grouped per (layer, wave, kk):
// Bg[((((l*16+w)*8+kk)*3+g)*64 + lane)*8 + e], bf16, log2e-prescaled.
#define NBGF  (NL * 16 * 8 * 3 * 512)      // 1,179,648 bf16
#define NBIAS (NL * 768)                    // fused (b_ih+b_hh)*scale, f32, [l][g][256]
#define NBINF (16 * 2 * 64 * 8)             // W_in  [fb][kk][lane][e], K 63->64
#define NBFCF (4 * 8 * 64 * 8)              // W_fc  [ff][kk][lane][e]

typedef __bf16 bf16_8 __attribute__((ext_vector_type(8)));
typedef __bf16 bf16_4 __attribute__((ext_vector_type(4)));
typedef float f32x4 __attribute__((ext_vector_type(4)));

#define LOG2E  1.4426950408889634f
#define LOG2E2 2.8853900817779268f

__device__ __forceinline__ unsigned short f2bf(float f) {
    unsigned int u = __float_as_uint(f);
    u = u + 0x7fffu + ((u >> 16) & 1u);   // RNE
    return (unsigned short)(u >> 16);
}

__global__ void prep_kernel(const float* __restrict__ W_in,
                            const float* __restrict__ W_ih,
                            const float* __restrict__ b_ih,
                            const float* __restrict__ b_hh,
                            const float* __restrict__ W_fc,
                            unsigned short* __restrict__ Bg,
                            float* __restrict__ bias,
                            unsigned short* __restrict__ Bin,
                            unsigned short* __restrict__ Bfc) {
    int idx = blockIdx.x * 256 + threadIdx.x;
    if (idx < NBGF) {
        int e    = idx & 7;
        int lane = (idx >> 3) & 63;
        int t    = idx >> 9;       // ((l*16+w)*8+kk)*3+g
        int g    = t % 3;
        int u    = t / 3;
        int kk   = u & 7;
        int v    = u >> 3;
        int w    = v & 15;
        int l    = v >> 4;
        int f = w * 16 + (lane & 15);
        int k = kk * 32 + (lane >> 4) * 8 + e;
        int r = f + (g == 0 ? 0 : (g == 1 ? 512 : 768));   // torch i,f,g,o; f dead
        float sc = (g == 1) ? LOG2E2 : LOG2E;
        Bg[idx] = f2bf(W_ih[((size_t)l * 1024 + r) * HSZ + k] * sc);
        return;
    }
    idx -= NBGF;
    if (idx < NBIAS) {
        int j = idx % 768, l = idx / 768;
        int g = j >> 8;
        int r = (j < 256) ? j : j + 256;
        float sc = (g == 1) ? LOG2E2 : LOG2E;
        bias[idx] = (b_ih[l * 1024 + r] + b_hh[l * 1024 + r]) * sc;
        return;
    }
    idx -= NBIAS;
    if (idx < NBINF) {
        int e = idx & 7, lane = (idx >> 3) & 63, kk = (idx >> 9) & 1, fb = idx >> 10;
        int f = fb * 16 + (lane & 15);
        int k = kk * 32 + (lane >> 4) * 8 + e;
        Bin[idx] = (k < DIO) ? f2bf(W_in[f * DIO + k]) : (unsigned short)0;
        return;
    }
    idx -= NBINF;
    if (idx < NBFCF) {
        int e = idx & 7, lane = (idx >> 3) & 63, kk = (idx >> 9) & 7, ff = idx >> 12;
        int f = ff * 16 + (lane & 15);
        int k = kk * 32 + (lane >> 4) * 8 + e;
        Bfc[idx] = (f < DIO) ? f2bf(W_fc[f * HSZ + k]) : (unsigned short)0;
    }
}

// act: c = sig(i)*tanh(g); h = sig(o)*tanh(c), tanh Pade(3,2) (err<=3e-4).
// No clamps (v10-v12-proven safe). Packed b64 writes.
__device__ __forceinline__ void act_write(char* nxt, int fb, int lq, int l15,
                                          f32x4 (&ai)[4], f32x4 (&ag)[4], f32x4 (&ao)[4]) {
    const int wrp = (fb >> 1) * 4096 + ((fb & 1) * 2 + (lq >> 1)) * 1024 +
                    l15 * 16 + (lq & 1) * 8;
#pragma unroll
    for (int n = 0; n < 4; ++n) {
        bf16_4 hv;
#pragma unroll
        for (int r = 0; r < 4; ++r) {
            float ei = __builtin_amdgcn_exp2f(ai[n][r]);
            float eg = __builtin_amdgcn_exp2f(ag[n][r]);
            float eo = __builtin_amdgcn_exp2f(ao[n][r]);
            float c = ei * (eg - 1.f) *
                      __builtin_amdgcn_rcpf((1.f + ei) * (1.f + eg));
            float z = c * c;
            hv[r] = (__bf16)(eo * c * (z + 15.f) *
                             __builtin_amdgcn_rcpf((1.f + eo) * fmaf(6.f, z, 15.f)));
        }
        *(bf16_4*)(nxt + wrp + n * 256) = hv;
    }
}

// v13 = v12 (16 waves/block, 32 waves/CU, 12-chain 16x16, 1 barrier/layer)
// + per-wave kk rotation (decorrelates post-barrier LDS/L2 bursts: at any
//   instant the block's waves touch 8 different kk regions; K-sum reorder
//   only, ~ulp numeric change)
// + s_setprio(1) around the MFMA cluster (T5; rotation creates the wave
//   role-diversity regime where setprio pays).
__global__ __launch_bounds__(THREADS, 4) void rnn_fused(
    const float* __restrict__ inp, const float* __restrict__ b_in,
    const float* __restrict__ b_fc,
    const unsigned short* __restrict__ Bg, const float* __restrict__ bias,
    const unsigned short* __restrict__ Bin, const unsigned short* __restrict__ Bfc,
    float* __restrict__ out) {
    __shared__ __align__(16) unsigned short h_lds[2 * 8 * 4 * 64 * 8];   // 64KB dbuf
    unsigned short* in_alias = h_lds + 16384;   // buf1; dead once layer0 writes

    const int tid = threadIdx.x;
    const int lane = tid & 63;
    const int l15 = lane & 15;
    const int lq = lane >> 4;
    const int wid = tid >> 6;          // 0..15: wave owns feats wid*16..+15, all 64 steps
    const int row0 = blockIdx.x * BM;
    const int rdB = lq * 1024 + l15 * 16;   // one base for all B-role LDS reads
    const int kr = wid & 7;                 // per-wave kk rotation

    // ---- stage input (64 x 63 fp32 -> bf16, K pad 64), [kk][lq][s][e] ----
    for (int idx = tid; idx < BM * 64; idx += THREADS) {
        int s = idx >> 6, k = idx & 63;
        float v = (k < DIO) ? inp[(size_t)(row0 + s) * DIO + k] : 0.f;
        int off = (k >> 5) * 4096 + ((k >> 3) & 3) * 1024 + s * 16 + (k & 7) * 2;
        *(unsigned short*)((char*)in_alias + off) = f2bf(v);
    }
    __syncthreads();

    // ---- input GEMM: x^T = W_in * inp^T + b_in -> buf0 ----
    {
        f32x4 acc[4];
        {
            f32x4 b4 = *(const f32x4*)(b_in + wid * 16 + lq * 4);
#pragma unroll
            for (int n = 0; n < 4; ++n) acc[n] = b4;
        }
        const bf16_8* __restrict__ pIA = (const bf16_8*)Bin + lane;
#pragma unroll
        for (int kk = 0; kk < 2; ++kk) {
            bf16_8 a = pIA[(wid * 2 + kk) * 64];
#pragma unroll
            for (int n = 0; n < 4; ++n) {
                bf16_8 b = *(const bf16_8*)((const char*)in_alias + rdB + kk * 4096 + n * 256);
                acc[n] = __builtin_amdgcn_mfma_f32_16x16x32_bf16(a, b, acc[n], 0, 0, 0);
            }
        }
        const int wrp = (wid >> 1) * 4096 + ((wid & 1) * 2 + (lq >> 1)) * 1024 +
                        l15 * 16 + (lq & 1) * 8;
#pragma unroll
        for (int n = 0; n < 4; ++n) {
            bf16_4 hv;
#pragma unroll
            for (int r = 0; r < 4; ++r) hv[r] = (__bf16)acc[n][r];
            *(bf16_4*)((char*)h_lds + wrp + n * 256) = hv;
        }
    }
    __syncthreads();

    // ---- 6 layers: one 16-feat pass per wave, 3 gates concurrent (12 chains),
    //      kk rotated per wave ----
    const char* Wb = (const char*)Bg + lane * 16;
    for (int l = 0; l < NL; ++l) {
        const char* cur = (const char*)h_lds + (l & 1) * 32768;
        char* nxt = (char*)h_lds + ((l + 1) & 1) * 32768;
        const char* pW = Wb + (size_t)(l * 16 + wid) * 24576;
        const float* pb = bias + l * 768 + wid * 16 + lq * 4;

        f32x4 ai[4], ag[4], ao[4];
        {
            f32x4 bi4 = *(const f32x4*)(pb);
            f32x4 bg4 = *(const f32x4*)(pb + 256);
            f32x4 bo4 = *(const f32x4*)(pb + 512);
#pragma unroll
            for (int n = 0; n < 4; ++n) { ai[n] = bi4; ag[n] = bg4; ao[n] = bo4; }
        }
        __builtin_amdgcn_s_setprio(1);
#pragma unroll
        for (int kk = 0; kk < 8; ++kk) {
            const int kx = (kk + kr) & 7;   // rotated K slot
            bf16_8 wa = *(const bf16_8*)(pW + kx * 3072);
            bf16_8 wg = *(const bf16_8*)(pW + kx * 3072 + 1024);
            bf16_8 wo = *(const bf16_8*)(pW + kx * 3072 + 2048);
            bf16_8 b[4];
#pragma unroll
            for (int n = 0; n < 4; ++n)
                b[n] = *(const bf16_8*)(cur + rdB + kx * 4096 + n * 256);
#pragma unroll
            for (int n = 0; n < 4; ++n) {
                ai[n] = __builtin_amdgcn_mfma_f32_16x16x32_bf16(wa, b[n], ai[n], 0, 0, 0);
                ag[n] = __builtin_amdgcn_mfma_f32_16x16x32_bf16(wg, b[n], ag[n], 0, 0, 0);
                ao[n] = __builtin_amdgcn_mfma_f32_16x16x32_bf16(wo, b[n], ao[n], 0, 0, 0);
            }
        }
        __builtin_amdgcn_s_setprio(0);
        act_write(nxt, wid, lq, l15, ai, ag, ao);
        __syncthreads();   // nxt published; cur free
    }

    // ---- final GEMM: out^T = W_fc * h^T + b_fc (buf0; all 16 waves) ----
    {
        const char* cur = (const char*)h_lds;
        const int ff = wid & 3;       // feature frag (16 feats)
        const int sf = wid >> 2;      // step frag (16 steps)
        f32x4 o4 = (f32x4){0.f, 0.f, 0.f, 0.f};
        const bf16_8* __restrict__ pF = (const bf16_8*)Bfc + lane;
#pragma unroll
        for (int kk = 0; kk < 8; ++kk) {
            const int kx = (kk + kr) & 7;
            bf16_8 a = pF[(ff * 8 + kx) * 64];
            bf16_8 b = *(const bf16_8*)(cur + rdB + kx * 4096 + sf * 256);
            o4 = __builtin_amdgcn_mfma_f32_16x16x32_bf16(a, b, o4, 0, 0, 0);
        }
        int s = row0 + sf * 16 + l15;
#pragma unroll
        for (int r = 0; r < 4; ++r) {
            int f = ff * 16 + lq * 4 + r;
            if (f < DIO) out[(size_t)s * DIO + f] = o4[r] + b_fc[f];
        }
    }
}

extern "C" void kernel_launch(void* const* d_in, const int* in_sizes, int n_in,
                              void* d_out, int out_size, void* d_ws, size_t ws_size,
                              hipStream_t stream) {
    const float* inputs = (const float*)d_in[0];
    const float* W_in   = (const float*)d_in[1];
    const float* b_in   = (const float*)d_in[2];
    const float* W_ih   = (const float*)d_in[3];
    // d_in[4] = W_hh: unused (h_prev == 0 every step)
    const float* b_ih   = (const float*)d_in[5];
    const float* b_hh   = (const float*)d_in[6];
    const float* W_fc   = (const float*)d_in[7];
    const float* b_fc   = (const float*)d_in[8];

    unsigned short* Bg  = (unsigned short*)d_ws;
    float* bias         = (float*)((char*)d_ws + (size_t)NBGF * 2);
    unsigned short* Bin = (unsigned short*)((char*)bias + (size_t)NBIAS * 4);
    unsigned short* Bfc = Bin + NBINF;

    int total = NBGF + NBIAS + NBINF + NBFCF;
    prep_kernel<<<(total + 255) / 256, 256, 0, stream>>>(W_in, W_ih, b_ih, b_hh, W_fc,
                                                         Bg, bias, Bin, Bfc);
    rnn_fused<<<STEPS / BM, THREADS, 0, stream>>>(inputs, b_in, b_fc, Bg, bias, Bin, Bfc,
                                                  (float*)d_out);
}

// Round 14
// 99.659 us; speedup vs baseline: 1.0221x; 1.0221x over previous
//
#include <hip/hip_runtime.h>

#define STEPS 32768
#define DIO 63
#define HSZ 256
#define NL 6
#define BM 64
#define THREADS 1024

// Gate weights, A-role fragment order, grouped per (layer, wave, kk):
// Bg[((((l*16+w)*8+kk)*3+g)*64 + lane)*8 + e], bf16, log2e-prescaled.
#define NBGF  (NL * 16 * 8 * 3 * 512)      // 1,179,648 bf16
#define NBIAS (NL * 768)                    // fused (b_ih+b_hh)*scale, f32, [l][g][256]
#define NBINF (16 * 2 * 64 * 8)             // W_in  [fb][kk][lane][e], K 63->64
#define NBFCF (4 * 8 * 64 * 8)              // W_fc  [ff][kk][lane][e]

typedef __bf16 bf16_8 __attribute__((ext_vector_type(8)));
typedef __bf16 bf16_4 __attribute__((ext_vector_type(4)));
typedef float f32x4 __attribute__((ext_vector_type(4)));

#define LOG2E  1.4426950408889634f
#define LOG2E2 2.8853900817779268f

__device__ __forceinline__ unsigned short f2bf(float f) {
    unsigned int u = __float_as_uint(f);
    u = u + 0x7fffu + ((u >> 16) & 1u);   // RNE
    return (unsigned short)(u >> 16);
}

__global__ void prep_kernel(const float* __restrict__ W_in,
                            const float* __restrict__ W_ih,
                            const float* __restrict__ b_ih,
                            const float* __restrict__ b_hh,
                            const float* __restrict__ W_fc,
                            unsigned short* __restrict__ Bg,
                            float* __restrict__ bias,
                            unsigned short* __restrict__ Bin,
                            unsigned short* __restrict__ Bfc) {
    int idx = blockIdx.x * 256 + threadIdx.x;
    if (idx < NBGF) {
        int e    = idx & 7;
        int lane = (idx >> 3) & 63;
        int t    = idx >> 9;       // ((l*16+w)*8+kk)*3+g
        int g    = t % 3;
        int u    = t / 3;
        int kk   = u & 7;
        int v    = u >> 3;
        int w    = v & 15;
        int l    = v >> 4;
        int f = w * 16 + (lane & 15);
        int k = kk * 32 + (lane >> 4) * 8 + e;
        int r = f + (g == 0 ? 0 : (g == 1 ? 512 : 768));   // torch i,f,g,o; f dead
        float sc = (g == 1) ? LOG2E2 : LOG2E;
        Bg[idx] = f2bf(W_ih[((size_t)l * 1024 + r) * HSZ + k] * sc);
        return;
    }
    idx -= NBGF;
    if (idx < NBIAS) {
        int j = idx % 768, l = idx / 768;
        int g = j >> 8;
        int r = (j < 256) ? j : j + 256;
        float sc = (g == 1) ? LOG2E2 : LOG2E;
        bias[idx] = (b_ih[l * 1024 + r] + b_hh[l * 1024 + r]) * sc;
        return;
    }
    idx -= NBIAS;
    if (idx < NBINF) {
        int e = idx & 7, lane = (idx >> 3) & 63, kk = (idx >> 9) & 1, fb = idx >> 10;
        int f = fb * 16 + (lane & 15);
        int k = kk * 32 + (lane >> 4) * 8 + e;
        Bin[idx] = (k < DIO) ? f2bf(W_in[f * DIO + k]) : (unsigned short)0;
        return;
    }
    idx -= NBINF;
    if (idx < NBFCF) {
        int e = idx & 7, lane = (idx >> 3) & 63, kk = (idx >> 9) & 7, ff = idx >> 12;
        int f = ff * 16 + (lane & 15);
        int k = kk * 32 + (lane >> 4) * 8 + e;
        Bfc[idx] = (f < DIO) ? f2bf(W_fc[f * HSZ + k]) : (unsigned short)0;
    }
}

// act: c = sig(i)*tanh(g); h = sig(o)*tanh(c), tanh Pade(3,2) (err<=3e-4).
// No clamps (v10-v13-proven safe). Packed b64 writes.
__device__ __forceinline__ void act_write(char* nxt, int fb, int lq, int l15,
                                          f32x4 (&ai)[4], f32x4 (&ag)[4], f32x4 (&ao)[4]) {
    const int wrp = (fb >> 1) * 4096 + ((fb & 1) * 2 + (lq >> 1)) * 1024 +
                    l15 * 16 + (lq & 1) * 8;
#pragma unroll
    for (int n = 0; n < 4; ++n) {
        bf16_4 hv;
#pragma unroll
        for (int r = 0; r < 4; ++r) {
            float ei = __builtin_amdgcn_exp2f(ai[n][r]);
            float eg = __builtin_amdgcn_exp2f(ag[n][r]);
            float eo = __builtin_amdgcn_exp2f(ao[n][r]);
            float c = ei * (eg - 1.f) *
                      __builtin_amdgcn_rcpf((1.f + ei) * (1.f + eg));
            float z = c * c;
            hv[r] = (__bf16)(eo * c * (z + 15.f) *
                             __builtin_amdgcn_rcpf((1.f + eo) * fmaf(6.f, z, 15.f)));
        }
        *(bf16_4*)(nxt + wrp + n * 256) = hv;
    }
}

// v14 = v12 exact revert (v13's kk-rotation + setprio were neutral-to-negative).
// Best measured config: 16 waves/block, 2 blocks/CU = 32 waves/CU (8/SIMD),
// 12-chain 16x16 MFMA, weight redundancy 1, 1 barrier/layer, VGPR 56.
// Structure sits at the serial-sum limit: MFMA ~37us + LDS ~31us + L2 ~34us
// ~= 99us measured; tiling-space optimum of the (reuse, redundancy) family.
__global__ __launch_bounds__(THREADS, 4) void rnn_fused(
    const float* __restrict__ inp, const float* __restrict__ b_in,
    const float* __restrict__ b_fc,
    const unsigned short* __restrict__ Bg, const float* __restrict__ bias,
    const unsigned short* __restrict__ Bin, const unsigned short* __restrict__ Bfc,
    float* __restrict__ out) {
    __shared__ __align__(16) unsigned short h_lds[2 * 8 * 4 * 64 * 8];   // 64KB dbuf
    unsigned short* in_alias = h_lds + 16384;   // buf1; dead once layer0 writes

    const int tid = threadIdx.x;
    const int lane = tid & 63;
    const int l15 = lane & 15;
    const int lq = lane >> 4;
    const int wid = tid >> 6;          // 0..15: wave owns feats wid*16..+15, all 64 steps
    const int row0 = blockIdx.x * BM;
    const int rdB = lq * 1024 + l15 * 16;   // one base for all B-role LDS reads

    // ---- stage input (64 x 63 fp32 -> bf16, K pad 64), [kk][lq][s][e] ----
    for (int idx = tid; idx < BM * 64; idx += THREADS) {
        int s = idx >> 6, k = idx & 63;
        float v = (k < DIO) ? inp[(size_t)(row0 + s) * DIO + k] : 0.f;
        int off = (k >> 5) * 4096 + ((k >> 3) & 3) * 1024 + s * 16 + (k & 7) * 2;
        *(unsigned short*)((char*)in_alias + off) = f2bf(v);
    }
    __syncthreads();

    // ---- input GEMM: x^T = W_in * inp^T + b_in -> buf0 ----
    {
        f32x4 acc[4];
        {
            f32x4 b4 = *(const f32x4*)(b_in + wid * 16 + lq * 4);
#pragma unroll
            for (int n = 0; n < 4; ++n) acc[n] = b4;
        }
        const bf16_8* __restrict__ pIA = (const bf16_8*)Bin + lane;
#pragma unroll
        for (int kk = 0; kk < 2; ++kk) {
            bf16_8 a = pIA[(wid * 2 + kk) * 64];
#pragma unroll
            for (int n = 0; n < 4; ++n) {
                bf16_8 b = *(const bf16_8*)((const char*)in_alias + rdB + kk * 4096 + n * 256);
                acc[n] = __builtin_amdgcn_mfma_f32_16x16x32_bf16(a, b, acc[n], 0, 0, 0);
            }
        }
        const int wrp = (wid >> 1) * 4096 + ((wid & 1) * 2 + (lq >> 1)) * 1024 +
                        l15 * 16 + (lq & 1) * 8;
#pragma unroll
        for (int n = 0; n < 4; ++n) {
            bf16_4 hv;
#pragma unroll
            for (int r = 0; r < 4; ++r) hv[r] = (__bf16)acc[n][r];
            *(bf16_4*)((char*)h_lds + wrp + n * 256) = hv;
        }
    }
    __syncthreads();

    // ---- 6 layers: one 16-feat pass per wave, 3 gates concurrent (12 chains) ----
    const char* Wb = (const char*)Bg + lane * 16;
    for (int l = 0; l < NL; ++l) {
        const char* cur = (const char*)h_lds + (l & 1) * 32768;
        char* nxt = (char*)h_lds + ((l + 1) & 1) * 32768;
        const char* pW = Wb + (size_t)(l * 16 + wid) * 24576;
        const float* pb = bias + l * 768 + wid * 16 + lq * 4;

        f32x4 ai[4], ag[4], ao[4];
        {
            f32x4 bi4 = *(const f32x4*)(pb);
            f32x4 bg4 = *(const f32x4*)(pb + 256);
            f32x4 bo4 = *(const f32x4*)(pb + 512);
#pragma unroll
            for (int n = 0; n < 4; ++n) { ai[n] = bi4; ag[n] = bg4; ao[n] = bo4; }
        }
#pragma unroll
        for (int kk = 0; kk < 8; ++kk) {
            bf16_8 wa = *(const bf16_8*)(pW + kk * 3072);
            bf16_8 wg = *(const bf16_8*)(pW + kk * 3072 + 1024);
            bf16_8 wo = *(const bf16_8*)(pW + kk * 3072 + 2048);
            bf16_8 b[4];
#pragma unroll
            for (int n = 0; n < 4; ++n)
                b[n] = *(const bf16_8*)(cur + rdB + kk * 4096 + n * 256);
#pragma unroll
            for (int n = 0; n < 4; ++n) {
                ai[n] = __builtin_amdgcn_mfma_f32_16x16x32_bf16(wa, b[n], ai[n], 0, 0, 0);
                ag[n] = __builtin_amdgcn_mfma_f32_16x16x32_bf16(wg, b[n], ag[n], 0, 0, 0);
                ao[n] = __builtin_amdgcn_mfma_f32_16x16x32_bf16(wo, b[n], ao[n], 0, 0, 0);
            }
        }
        act_write(nxt, wid, lq, l15, ai, ag, ao);
        __syncthreads();   // nxt published; cur free
    }

    // ---- final GEMM: out^T = W_fc * h^T + b_fc (buf0; all 16 waves) ----
    {
        const char* cur = (const char*)h_lds;
        const int ff = wid & 3;       // feature frag (16 feats)
        const int sf = wid >> 2;      // step frag (16 steps)
        f32x4 o4 = (f32x4){0.f, 0.f, 0.f, 0.f};
        const bf16_8* __restrict__ pF = (const bf16_8*)Bfc + lane;
#pragma unroll
        for (int kk = 0; kk < 8; ++kk) {
            bf16_8 a = pF[(ff * 8 + kk) * 64];
            bf16_8 b = *(const bf16_8*)(cur + rdB + kk * 4096 + sf * 256);
            o4 = __builtin_amdgcn_mfma_f32_16x16x32_bf16(a, b, o4, 0, 0, 0);
        }
        int s = row0 + sf * 16 + l15;
#pragma unroll
        for (int r = 0; r < 4; ++r) {
            int f = ff * 16 + lq * 4 + r;
            if (f < DIO) out[(size_t)s * DIO + f] = o4[r] + b_fc[f];
        }
    }
}

extern "C" void kernel_launch(void* const* d_in, const int* in_sizes, int n_in,
                              void* d_out, int out_size, void* d_ws, size_t ws_size,
                              hipStream_t stream) {
    const float* inputs = (const float*)d_in[0];
    const float* W_in   = (const float*)d_in[1];
    const float* b_in   = (const float*)d_in[2];
    const float* W_ih   = (const float*)d_in[3];
    // d_in[4] = W_hh: unused (h_prev == 0 every step)
    const float* b_ih   = (const float*)d_in[5];
    const float* b_hh   = (const float*)d_in[6];
    const float* W_fc   = (const float*)d_in[7];
    const float* b_fc   = (const float*)d_in[8];

    unsigned short* Bg  = (unsigned short*)d_ws;
    float* bias         = (float*)((char*)d_ws + (size_t)NBGF * 2);
    unsigned short* Bin = (unsigned short*)((char*)bias + (size_t)NBIAS * 4);
    unsigned short* Bfc = Bin + NBINF;

    int total = NBGF + NBIAS + NBINF + NBFCF;
    prep_kernel<<<(total + 255) / 256, 256, 0, stream>>>(W_in, W_ih, b_ih, b_hh, W_fc,
                                                         Bg, bias, Bin, Bfc);
    rnn_fused<<<STEPS / BM, THREADS, 0, stream>>>(inputs, b_in, b_fc, Bg, bias, Bin, Bfc,
                                                  (float*)d_out);
}